// Round 7
// baseline (455.505 us; speedup 1.0000x reference)
//
#include <hip/hip_runtime.h>
#include <hip/hip_bf16.h>

#define NN 50000
#define DD 64
#define EE 800000
#define NTILE 3125   // NN/16 row tiles (exact)
#define NBLKL 391    // ceil(NTILE/8) linear blocks (8 tiles/block, 2/wave)
#define RN 128       // nodes per dst-range
#define NR 391       // ceil(NN/RN) ranges (last has 80 nodes)
#define CAP 3072     // edge capacity per range (mean 2048, sigma~45 -> +22sigma)
#define NBB 256      // bin blocks
#define EPB 3125     // EE/NBB edges per bin block

typedef unsigned short u16;
typedef unsigned int u32;
typedef __attribute__((ext_vector_type(8))) short bf16x8;
typedef __attribute__((ext_vector_type(4))) float f32x4;

__device__ __forceinline__ float bf2f(u16 u) {
  u32 t = ((u32)u) << 16;
  return __builtin_bit_cast(float, t);
}
__device__ __forceinline__ u16 f2bf(float f) {
  u32 b = __builtin_bit_cast(u32, f);
  u32 r = (b + 0x7FFF + ((b >> 16) & 1)) >> 16;
  return (u16)r;
}

// ---------------------------------------------------------------------------
// Kernel 1 (MFMA): x = nf @ W.T + b_lin, bf16 out. Block 0 inits gcur.
// 2 row-tiles per wave (8/block). C/D: col=lane&15, row=(lane>>4)*4+reg.
// ---------------------------------------------------------------------------
__global__ __launch_bounds__(256) void linear_mfma_kernel(
    const float* __restrict__ nf, const float* __restrict__ W,
    const float* __restrict__ b_lin, u16* __restrict__ x16,
    int* __restrict__ gcur) {
  __shared__ u16 Wsh[64 * 72];
  int tid = threadIdx.x;

  if (blockIdx.x == 0) {  // init per-range segment cursors
    for (int t = tid; t < NR; t += 256) gcur[t] = t * CAP;
  }

#pragma unroll
  for (int s = 0; s < 16; ++s) {
    int idx = s * 256 + tid;
    int j = idx >> 6, k = idx & 63;
    Wsh[j * 72 + k] = f2bf(W[idx]);
  }
  __syncthreads();

  int wave = tid >> 6;
  int lane = tid & 63;
  int m = lane & 15;
  int quad = lane >> 4;

  bf16x8 bfrag[4][2];
#pragma unroll
  for (int c = 0; c < 4; ++c) {
#pragma unroll
    for (int ks = 0; ks < 2; ++ks) {
      const u16* p = &Wsh[(c * 16 + m) * 72 + ks * 32 + quad * 8];
      bfrag[c][ks] = *(const bf16x8*)p;
    }
  }

#pragma unroll
  for (int tt = 0; tt < 2; ++tt) {
    int tile = blockIdx.x * 8 + wave * 2 + tt;
    if (tile >= NTILE) continue;
    int rowbase = tile * 16;

    bf16x8 afrag[2];
#pragma unroll
    for (int ks = 0; ks < 2; ++ks) {
      const float* p = nf + (rowbase + m) * DD + ks * 32 + quad * 8;
      float4 lo = *(const float4*)p;
      float4 hi = *(const float4*)(p + 4);
      bf16x8 a;
      a[0] = (short)f2bf(lo.x); a[1] = (short)f2bf(lo.y);
      a[2] = (short)f2bf(lo.z); a[3] = (short)f2bf(lo.w);
      a[4] = (short)f2bf(hi.x); a[5] = (short)f2bf(hi.y);
      a[6] = (short)f2bf(hi.z); a[7] = (short)f2bf(hi.w);
      afrag[ks] = a;
    }

    f32x4 acc[4];
#pragma unroll
    for (int c = 0; c < 4; ++c) {
      acc[c][0] = 0.0f; acc[c][1] = 0.0f; acc[c][2] = 0.0f; acc[c][3] = 0.0f;
    }
#pragma unroll
    for (int c = 0; c < 4; ++c) {
      acc[c] = __builtin_amdgcn_mfma_f32_16x16x32_bf16(afrag[0], bfrag[c][0], acc[c], 0, 0, 0);
      acc[c] = __builtin_amdgcn_mfma_f32_16x16x32_bf16(afrag[1], bfrag[c][1], acc[c], 0, 0, 0);
    }

#pragma unroll
    for (int c = 0; c < 4; ++c) {
      int gcol = c * 16 + m;
      float bl = b_lin[gcol];
#pragma unroll
      for (int r = 0; r < 4; ++r) {
        int grow = rowbase + quad * 4 + r;
        x16[grow * DD + gcol] = f2bf(acc[c][r] + bl);
      }
    }
  }
}

// ---------------------------------------------------------------------------
// Kernel 2: bin edges into NR dst-ranges. Per block: LDS hist over ranges ->
// ONE global atomic reservation per (block,range) -> packed writes.
// Packed entry: src<<7 | (dst&127). ~100k global atomics total (vs 1.6M CSR).
// ---------------------------------------------------------------------------
__global__ __launch_bounds__(256) void bin_kernel(
    const int* __restrict__ ei, int* __restrict__ gcur,
    u32* __restrict__ be) {
  __shared__ int hist[NR];
  __shared__ int gbase[NR];
  int tid = threadIdx.x;
  int ebase = blockIdx.x * EPB;

  for (int t = tid; t < NR; t += 256) hist[t] = 0;
  __syncthreads();

#pragma unroll 1
  for (int it = 0; it < 13; ++it) {
    int e = ebase + it * 256 + tid;
    if (e < ebase + EPB) {
      int2 p = *(const int2*)(ei + 2 * e);  // (src,dst)
      atomicAdd(&hist[p.y >> 7], 1);
    }
  }
  __syncthreads();

  for (int t = tid; t < NR; t += 256) {
    gbase[t] = atomicAdd(&gcur[t], hist[t]);
    hist[t] = 0;  // reuse as local cursor
  }
  __syncthreads();

#pragma unroll 1
  for (int it = 0; it < 13; ++it) {
    int e = ebase + it * 256 + tid;
    if (e < ebase + EPB) {
      int2 p = *(const int2*)(ei + 2 * e);
      int r = p.y >> 7;
      int lofs = atomicAdd(&hist[r], 1);
      be[gbase[r] + lofs] = ((u32)p.x << 7) | (u32)(p.y & 127);
    }
  }
}

// ---------------------------------------------------------------------------
// Kernel 3: accumulate + finalize. One block per range: LDS fp32 acc[128][64]
// (lane j -> bank j%32, 2-way = free) + ldeg[128]. Coalesced 64-index loads,
// readlane -> SGPR src/dl; 16-deep batches of independent row loads, then
// ds atomic adds. Epilogue: out = relu(self + acc/max(deg,1) + bias).
// ---------------------------------------------------------------------------
__global__ __launch_bounds__(256) void accum_kernel(
    const u16* __restrict__ x16, const u32* __restrict__ be,
    const int* __restrict__ gcur, const float* __restrict__ bias,
    float* __restrict__ out) {
  __shared__ float acc[RN * 64];
  __shared__ float ldeg[RN];
  int tid = threadIdx.x;
  int w = tid >> 6;
  int j = tid & 63;
  int r = blockIdx.x;

  for (int t = tid; t < RN * 64; t += 256) acc[t] = 0.0f;
  for (int t = tid; t < RN; t += 256) ldeg[t] = 0.0f;
  __syncthreads();

  const u32* mybe = be + r * CAP;
  int M = __builtin_amdgcn_readfirstlane(gcur[r]) - r * CAP;

#pragma unroll 1
  for (int base = w * 64; base < M; base += 256) {
    u32 my = mybe[base + j];  // coalesced 256 B; lanes >= win gated below
    int win = M - base;
    win = win > 64 ? 64 : win;
#pragma unroll
    for (int b0 = 0; b0 < 64; b0 += 16) {
      if (b0 < win) {  // wave-uniform
        float v[16];
        int dls[16];   // uniform -> SGPRs
#pragma unroll
        for (int k = 0; k < 16; ++k) {
          int kk = b0 + k;
          int cl = kk < win ? kk : win - 1;  // clamp: dup row, L1-hot
          u32 val = (u32)__builtin_amdgcn_readlane((int)my, cl);
          int s = (int)(val >> 7);
          dls[k] = (int)(val & 127);
          v[k] = bf2f(x16[s * DD + j]);
        }
#pragma unroll
        for (int k = 0; k < 16; ++k) {
          int kk = b0 + k;
          if (kk < win) {  // wave-uniform
            atomicAdd(&acc[dls[k] * 64 + j], v[k]);
            if (j == 0) atomicAdd(&ldeg[dls[k]], 1.0f);
          }
        }
      }
    }
  }
  __syncthreads();

  // epilogue: wave w handles nodes w*32 .. w*32+31 of this range
  float bj = bias[j];
#pragma unroll 1
  for (int it = 0; it < 32; ++it) {
    int n = w * 32 + it;
    int g = r * RN + n;
    if (g < NN) {
      float d = fmaxf(ldeg[n], 1.0f);
      float inv = 1.0f / d;
      float agg = acc[n * 64 + j];
      float self = bf2f(x16[g * DD + j]);
      out[g * DD + j] = fmaxf(fmaf(agg, inv, self + bj), 0.0f);
    }
  }
}

extern "C" void kernel_launch(void* const* d_in, const int* in_sizes, int n_in,
                              void* d_out, int out_size, void* d_ws, size_t ws_size,
                              hipStream_t stream) {
  const float* nf    = (const float*)d_in[0];
  const int*   ei    = (const int*)d_in[1];
  const float* W     = (const float*)d_in[2];
  const float* b_lin = (const float*)d_in[3];
  const float* bias  = (const float*)d_in[4];
  float* out = (float*)d_out;

  // workspace layout
  u16* x16 = (u16*)d_ws;                    // N*D bf16      (6.4 MB)
  u32* be  = (u32*)(x16 + (size_t)NN * DD); // NR*CAP u32    (4.8 MB)
  int* gcur = (int*)(be + (size_t)NR * CAP);// NR ints
  // total ~11.2 MB << ws_size

  linear_mfma_kernel<<<NBLKL, 256, 0, stream>>>(nf, W, b_lin, x16, gcur);
  bin_kernel<<<NBB, 256, 0, stream>>>(ei, gcur, be);
  accum_kernel<<<NR, 256, 0, stream>>>(x16, be, gcur, bias, out);
}

// Round 8
// 441.773 us; speedup vs baseline: 1.0311x; 1.0311x over previous
//
#include <hip/hip_runtime.h>
#include <hip/hip_bf16.h>

#define NN 50000
#define DD 64
#define EE 800000
#define NTILE 3125   // NN/16 row tiles (exact)
#define NBLKL 391    // linear blocks (8 tiles/block, 2/wave)
#define NBINB 128    // bin blocks
#define EPB 6250     // EE/NBINB edges per bin block
#define RN 128       // nodes per dst-range
#define NR 391       // ceil(NN/RN) ranges
#define QUOTA 64     // entries per (bin-block, range) cell; Binom(6250,1/391)
                     // mean 16, sd 4 -> 64 = +12 sigma, never hit
#define CELLSTRIDE (NBINB * QUOTA)  // 8192 entries per range

typedef unsigned short u16;
typedef unsigned int u32;
typedef __attribute__((ext_vector_type(8))) short bf16x8;
typedef __attribute__((ext_vector_type(4))) float f32x4;

__device__ __forceinline__ float bf2f(u16 u) {
  u32 t = ((u32)u) << 16;
  return __builtin_bit_cast(float, t);
}
__device__ __forceinline__ u16 f2bf(float f) {
  u32 b = __builtin_bit_cast(u32, f);
  u32 r = (b + 0x7FFF + ((b >> 16) & 1)) >> 16;
  return (u16)r;
}

// ---------------------------------------------------------------------------
// D1: blocks [0,NBLKL) do the MFMA linear; blocks [NBLKL,NBLKL+NBINB) bin the
// edge list. Independent work, one dispatch, fully concurrent.
//
// bin: block b owns exclusive cells be[r*CELLSTRIDE + b*QUOTA .. +QUOTA).
// One pass: LDS cursor per range, no global atomics, no init needed.
// Entry packs src<<7 | dst_local. Counts -> cntbr[b*NR + r] (overwritten,
// poison-safe).
// ---------------------------------------------------------------------------
__global__ __launch_bounds__(256) void linear_bin_kernel(
    const float* __restrict__ nf, const float* __restrict__ W,
    const float* __restrict__ b_lin, const int* __restrict__ ei,
    u16* __restrict__ x16, u32* __restrict__ be, u16* __restrict__ cntbr) {
  __shared__ u16 Wsh[64 * 72];
  __shared__ int lcur[NR];
  int tid = threadIdx.x;

  if (blockIdx.x >= NBLKL) {
    // ---- bin path ----
    int b = blockIdx.x - NBLKL;
    for (int t = tid; t < NR; t += 256) lcur[t] = 0;
    __syncthreads();
    int ebase = b * EPB;
#pragma unroll 1
    for (int it = 0; it < 25; ++it) {
      int e = ebase + it * 256 + tid;
      if (e < ebase + EPB) {
        int2 p = *(const int2*)(ei + 2 * e);  // (src, dst)
        int r = p.y >> 7;
        int lofs = atomicAdd(&lcur[r], 1);
        if (lofs < QUOTA)
          be[r * CELLSTRIDE + b * QUOTA + lofs] =
              ((u32)p.x << 7) | (u32)(p.y & 127);
      }
    }
    __syncthreads();
    for (int t = tid; t < NR; t += 256) {
      int c = lcur[t];
      cntbr[b * NR + t] = (u16)(c > QUOTA ? QUOTA : c);
    }
    return;
  }

  // ---- linear path (R6-proven) ----
#pragma unroll
  for (int s = 0; s < 16; ++s) {
    int idx = s * 256 + tid;
    int j = idx >> 6, k = idx & 63;
    Wsh[j * 72 + k] = f2bf(W[idx]);
  }
  __syncthreads();

  int wave = tid >> 6;
  int lane = tid & 63;
  int m = lane & 15;
  int quad = lane >> 4;

  bf16x8 bfrag[4][2];
#pragma unroll
  for (int c = 0; c < 4; ++c) {
#pragma unroll
    for (int ks = 0; ks < 2; ++ks) {
      const u16* p = &Wsh[(c * 16 + m) * 72 + ks * 32 + quad * 8];
      bfrag[c][ks] = *(const bf16x8*)p;
    }
  }

#pragma unroll
  for (int tt = 0; tt < 2; ++tt) {
    int tile = blockIdx.x * 8 + wave * 2 + tt;
    if (tile >= NTILE) continue;
    int rowbase = tile * 16;

    bf16x8 afrag[2];
#pragma unroll
    for (int ks = 0; ks < 2; ++ks) {
      const float* p = nf + (rowbase + m) * DD + ks * 32 + quad * 8;
      float4 lo = *(const float4*)p;
      float4 hi = *(const float4*)(p + 4);
      bf16x8 a;
      a[0] = (short)f2bf(lo.x); a[1] = (short)f2bf(lo.y);
      a[2] = (short)f2bf(lo.z); a[3] = (short)f2bf(lo.w);
      a[4] = (short)f2bf(hi.x); a[5] = (short)f2bf(hi.y);
      a[6] = (short)f2bf(hi.z); a[7] = (short)f2bf(hi.w);
      afrag[ks] = a;
    }

    f32x4 acc[4];
#pragma unroll
    for (int c = 0; c < 4; ++c) {
      acc[c][0] = 0.0f; acc[c][1] = 0.0f; acc[c][2] = 0.0f; acc[c][3] = 0.0f;
    }
#pragma unroll
    for (int c = 0; c < 4; ++c) {
      acc[c] = __builtin_amdgcn_mfma_f32_16x16x32_bf16(afrag[0], bfrag[c][0], acc[c], 0, 0, 0);
      acc[c] = __builtin_amdgcn_mfma_f32_16x16x32_bf16(afrag[1], bfrag[c][1], acc[c], 0, 0, 0);
    }

#pragma unroll
    for (int c = 0; c < 4; ++c) {
      int gcol = c * 16 + m;
      float bl = b_lin[gcol];
#pragma unroll
      for (int r = 0; r < 4; ++r) {
        int grow = rowbase + quad * 4 + r;
        x16[grow * DD + gcol] = f2bf(acc[c][r] + bl);
      }
    }
  }
}

// ---------------------------------------------------------------------------
// D2: accumulate + finalize. One 1024-thread block (16 waves, 32KB LDS acc ->
// 2 blocks/CU = 32 waves/CU) per range. Wave w handles cells w, w+16, ...
// SCALARIZATION DISCIPLINE (the R7 lesson): w and cnt go through
// readfirstlane so every readlane lane-select and loop bound is SGPR —
// no waterfall loops. Row loads: 16-deep MLP, scalar-base + lane-j offset.
// ---------------------------------------------------------------------------
__global__ __launch_bounds__(1024) void accum_kernel(
    const u16* __restrict__ x16, const u32* __restrict__ be,
    const u16* __restrict__ cntbr, const float* __restrict__ bias,
    float* __restrict__ out) {
  __shared__ float acc[RN * 64];  // 32 KB
  __shared__ float ldeg[RN];
  int tid = threadIdx.x;
  int j = tid & 63;
  int w = __builtin_amdgcn_readfirstlane(tid >> 6);  // wave id, SGPR
  int r = blockIdx.x;

  for (int t = tid; t < RN * 64; t += 1024) acc[t] = 0.0f;
  if (tid < RN) ldeg[tid] = 0.0f;
  __syncthreads();

#pragma unroll 1
  for (int cb = 0; cb < NBINB; cb += 16) {
    int b = cb + w;  // SGPR
    int cnt = __builtin_amdgcn_readfirstlane((int)cntbr[b * NR + r]);
    const u32* cell = be + (size_t)r * CELLSTRIDE + b * QUOTA;
    u32 my = cell[j];  // coalesced 256 B; entries >= cnt stale, gated below
#pragma unroll 1
    for (int s0 = 0; s0 < QUOTA; s0 += 16) {
      if (s0 < cnt) {  // scalar branch; usually only s0=0 taken (cnt~16)
        float v[16];
        int dl[16];  // scalar (derived from readlane result)
#pragma unroll
        for (int k = 0; k < 16; ++k) {
          int kk = s0 + k;
          int cl = kk < cnt ? kk : cnt - 1;  // SGPR clamp (dup row, L1-hot)
          u32 val = (u32)__builtin_amdgcn_readlane((int)my, cl);
          int src = (int)(val >> 7);
          dl[k] = (int)(val & 127);
          v[k] = bf2f(x16[src * DD + j]);  // scalar base + lane offset
        }
#pragma unroll
        for (int k = 0; k < 16; ++k) {
          int kk = s0 + k;
          if (kk < cnt) {  // scalar
            atomicAdd(&acc[dl[k] * 64 + j], v[k]);
            if (j == 0) atomicAdd(&ldeg[dl[k]], 1.0f);
          }
        }
      }
    }
  }
  __syncthreads();

  // epilogue: wave w -> nodes w*8 .. w*8+7 of this range
  float bj = bias[j];
#pragma unroll 1
  for (int t = 0; t < 8; ++t) {
    int n = w * 8 + t;
    int g = r * RN + n;
    if (g < NN) {
      float d = fmaxf(ldeg[n], 1.0f);
      float agg = acc[n * 64 + j] / d;
      float self = bf2f(x16[g * DD + j]);
      out[g * DD + j] = fmaxf(agg + self + bj, 0.0f);
    }
  }
}

extern "C" void kernel_launch(void* const* d_in, const int* in_sizes, int n_in,
                              void* d_out, int out_size, void* d_ws, size_t ws_size,
                              hipStream_t stream) {
  const float* nf    = (const float*)d_in[0];
  const int*   ei    = (const int*)d_in[1];
  const float* W     = (const float*)d_in[2];
  const float* b_lin = (const float*)d_in[3];
  const float* bias  = (const float*)d_in[4];
  float* out = (float*)d_out;

  // workspace layout
  u16* x16   = (u16*)d_ws;                         // N*D bf16        (6.4 MB)
  u32* be    = (u32*)(x16 + (size_t)NN * DD);      // NR*CELLSTRIDE  (12.8 MB)
  u16* cntbr = (u16*)(be + (size_t)NR * CELLSTRIDE);  // NBINB*NR     (100 KB)
  // total ~19.3 MB << ws_size; no memset needed (cells overwritten or gated)

  linear_bin_kernel<<<NBLKL + NBINB, 256, 0, stream>>>(nf, W, b_lin, ei, x16,
                                                       be, cntbr);
  accum_kernel<<<NR, 1024, 0, stream>>>(x16, be, cntbr, bias, out);
}

// Round 9
// 203.422 us; speedup vs baseline: 2.2392x; 2.1717x over previous
//
#include <hip/hip_runtime.h>
#include <hip/hip_bf16.h>

#define NN 50000
#define DD 64
#define EE 800000
#define NB 196      // ceil(NN/256) scan blocks
#define NTILE 3125  // NN/16 row tiles (exact)
#define NBLKL 391   // linear blocks (8 tiles/block, 2/wave)
#define NHIST 782   // ceil(EE/4/256) hist blocks (4 edges/thread)
#define NSLICE 128  // edge slices for scatter
#define ESL 6250    // EE/NSLICE edges per slice
#define DRNG 6250   // NN/8 dst nodes per XCD range

typedef unsigned short u16;
typedef unsigned int u32;
typedef __attribute__((ext_vector_type(8))) short bf16x8;
typedef __attribute__((ext_vector_type(4))) float f32x4;

__device__ __forceinline__ float bf2f(u16 u) {
  u32 t = ((u32)u) << 16;
  return __builtin_bit_cast(float, t);
}
__device__ __forceinline__ u16 f2bf(float f) {
  u32 b = __builtin_bit_cast(u32, f);
  u32 r = (b + 0x7FFF + ((b >> 16) & 1)) >> 16;
  return (u16)r;
}

// ---------------------------------------------------------------------------
// D1: blocks [0,NBLKL) = MFMA linear (R6-proven); blocks [NBLKL,..) = hist
// (4 edges/thread, global atomics on cnt). Disjoint resources -> concurrent.
// cnt is zeroed by a preceding 200 KB memset (same-dispatch zeroing would
// race with hist).
// ---------------------------------------------------------------------------
__global__ __launch_bounds__(256) void linear_hist_kernel(
    const float* __restrict__ nf, const float* __restrict__ W,
    const float* __restrict__ b_lin, const int* __restrict__ ei,
    u16* __restrict__ x16, int* __restrict__ cnt) {
  __shared__ u16 Wsh[64 * 72];
  int tid = threadIdx.x;

  if (blockIdx.x >= NBLKL) {
    // ---- hist path ----
    int e = ((int)(blockIdx.x - NBLKL) * 256 + tid) * 4;
    if (e < EE) {
      int4 a = *(const int4*)(ei + 2 * e);
      int4 b = *(const int4*)(ei + 2 * e + 4);
      atomicAdd(&cnt[a.y], 1);
      atomicAdd(&cnt[a.w], 1);
      atomicAdd(&cnt[b.y], 1);
      atomicAdd(&cnt[b.w], 1);
    }
    return;
  }

  // ---- linear path (R6-proven) ----
#pragma unroll
  for (int s = 0; s < 16; ++s) {
    int idx = s * 256 + tid;
    int j = idx >> 6, k = idx & 63;
    Wsh[j * 72 + k] = f2bf(W[idx]);
  }
  __syncthreads();

  int wave = tid >> 6;
  int lane = tid & 63;
  int m = lane & 15;
  int quad = lane >> 4;

  bf16x8 bfrag[4][2];
#pragma unroll
  for (int c = 0; c < 4; ++c) {
#pragma unroll
    for (int ks = 0; ks < 2; ++ks) {
      const u16* p = &Wsh[(c * 16 + m) * 72 + ks * 32 + quad * 8];
      bfrag[c][ks] = *(const bf16x8*)p;
    }
  }

#pragma unroll
  for (int tt = 0; tt < 2; ++tt) {
    int tile = blockIdx.x * 8 + wave * 2 + tt;
    if (tile >= NTILE) continue;
    int rowbase = tile * 16;

    bf16x8 afrag[2];
#pragma unroll
    for (int ks = 0; ks < 2; ++ks) {
      const float* p = nf + (rowbase + m) * DD + ks * 32 + quad * 8;
      float4 lo = *(const float4*)p;
      float4 hi = *(const float4*)(p + 4);
      bf16x8 a;
      a[0] = (short)f2bf(lo.x); a[1] = (short)f2bf(lo.y);
      a[2] = (short)f2bf(lo.z); a[3] = (short)f2bf(lo.w);
      a[4] = (short)f2bf(hi.x); a[5] = (short)f2bf(hi.y);
      a[6] = (short)f2bf(hi.z); a[7] = (short)f2bf(hi.w);
      afrag[ks] = a;
    }

    f32x4 acc[4];
#pragma unroll
    for (int c = 0; c < 4; ++c) {
      acc[c][0] = 0.0f; acc[c][1] = 0.0f; acc[c][2] = 0.0f; acc[c][3] = 0.0f;
    }
#pragma unroll
    for (int c = 0; c < 4; ++c) {
      acc[c] = __builtin_amdgcn_mfma_f32_16x16x32_bf16(afrag[0], bfrag[c][0], acc[c], 0, 0, 0);
      acc[c] = __builtin_amdgcn_mfma_f32_16x16x32_bf16(afrag[1], bfrag[c][1], acc[c], 0, 0, 0);
    }

#pragma unroll
    for (int c = 0; c < 4; ++c) {
      int gcol = c * 16 + m;
      float bl = b_lin[gcol];
#pragma unroll
      for (int r = 0; r < 4; ++r) {
        int grow = rowbase + quad * 4 + r;
        x16[grow * DD + gcol] = f2bf(acc[c][r] + bl);
      }
    }
  }
}

// ---------------------------------------------------------------------------
// D2: single-dispatch scan. Block g: (a) sum cnt[0 .. g*256) via strided
// coalesced loads + LDS tree-reduce (L2-served, <=50k loads, ~1 us);
// (b) exclusive-scan its own 256-chunk; write csr_off + cur.
// ---------------------------------------------------------------------------
__global__ __launch_bounds__(256) void scan_kernel(
    const int* __restrict__ cnt, int* __restrict__ csr_off,
    int* __restrict__ cur) {
  __shared__ int s[256];
  int t = threadIdx.x;
  int lim = (int)blockIdx.x << 8;  // multiple of 256

  int part = 0;
  for (int i = t; i < lim; i += 256) part += cnt[i];
  s[t] = part;
  __syncthreads();
#pragma unroll
  for (int o = 128; o > 0; o >>= 1) {
    if (t < o) s[t] += s[t + o];
    __syncthreads();
  }
  int base = s[0];
  __syncthreads();

  int i = lim + t;
  int v = (i < NN) ? cnt[i] : 0;
  s[t] = v;
  __syncthreads();
#pragma unroll
  for (int o = 1; o < 256; o <<= 1) {
    int u = (t >= o) ? s[t - o] : 0;
    __syncthreads();
    s[t] += u;
    __syncthreads();
  }
  int off = base + s[t] - v;  // exclusive scan of cnt
  if (i < NN) {
    csr_off[i] = off;
    cur[i] = off;
    if (i == NN - 1) csr_off[NN] = off + v;  // == EE
  }
}

// ---------------------------------------------------------------------------
// D3: scatter, XCD-sliced (R6-proven). Block b: dst range r=b&7, edge slice
// sl=b>>3. Range's csr_src region + cur counters served by one XCD's L2
// (heuristic; correctness mapping-agnostic).
// ---------------------------------------------------------------------------
__global__ __launch_bounds__(256) void scatter_kernel(
    const int* __restrict__ ei, int* __restrict__ cur,
    u16* __restrict__ csr_src) {
  int r = blockIdx.x & 7;
  int sl = blockIdx.x >> 3;
  int rlo = r * DRNG;
  int ebase = sl * ESL;
  int eend = ebase + ESL;
#pragma unroll 1
  for (int it = 0; it < 13; ++it) {
    int e = ebase + it * 512 + (int)threadIdx.x * 2;
    if (e < eend) {
      int4 p = *(const int4*)(ei + 2 * e);  // (src0,dst0,src1,dst1)
      if ((u32)(p.y - rlo) < (u32)DRNG) {
        int pos = atomicAdd(&cur[p.y], 1);
        csr_src[pos] = (u16)p.x;
      }
      if ((u32)(p.w - rlo) < (u32)DRNG) {
        int pos = atomicAdd(&cur[p.w], 1);
        csr_src[pos] = (u16)p.z;
      }
    }
  }
}

// ---------------------------------------------------------------------------
// D4: gather (R6-proven). One wave per node; coalesced 128 B index load,
// readlane->SGPR broadcast (loads issue independently, MLP = deg), lanes
// beyond deg clamped to last valid edge (dup row, L1-hot), gated adds.
// ---------------------------------------------------------------------------
__device__ __forceinline__ void loadchunk(int my, int win, int base,
                                          const u16* __restrict__ x16, int j,
                                          float* v) {
#pragma unroll
  for (int k = 0; k < 16; ++k) {
    int kk = base + k;
    int cl = (kk < win) ? kk : (win - 1);  // scalar clamp
    int s = __builtin_amdgcn_readlane(my, cl);
    v[kk] = bf2f(x16[s * DD + j]);
  }
}
__device__ __forceinline__ float sum16(const float* v, int base, int win) {
  float a = 0.0f;
#pragma unroll
  for (int k = 0; k < 16; ++k) {
    int kk = base + k;
    a += (kk < win) ? v[kk] : 0.0f;
  }
  return a;
}

__global__ __launch_bounds__(256) void gather_kernel(
    const u16* __restrict__ x16, const u16* __restrict__ csr_src,
    const int* __restrict__ csr_off, const float* __restrict__ bias,
    float* __restrict__ out) {
  int i = blockIdx.x * 4 + (threadIdx.x >> 6);  // grid exact: NN/4 blocks
  int j = threadIdx.x & 63;
  int beg = __builtin_amdgcn_readfirstlane(csr_off[i]);
  int end = __builtin_amdgcn_readfirstlane(csr_off[i + 1]);
  float acc = 0.0f;
  int pos = beg;
#pragma unroll 1
  while (pos < end) {  // 1 iteration for deg<=64 (always, in practice)
    int my = (int)csr_src[pos + j];  // csr_src padded by 64 entries
    int win = end - pos;
    win = win > 64 ? 64 : win;
    int nc = (win + 15) >> 4;
    float v[64];
    loadchunk(my, win, 0, x16, j, v);
    if (nc > 1) loadchunk(my, win, 16, x16, j, v);
    if (nc > 2) loadchunk(my, win, 32, x16, j, v);
    if (nc > 3) loadchunk(my, win, 48, x16, j, v);
    acc += sum16(v, 0, win);
    if (nc > 1) acc += sum16(v, 16, win);
    if (nc > 2) acc += sum16(v, 32, win);
    if (nc > 3) acc += sum16(v, 48, win);
    pos += 64;
  }
  float deg = (float)(end - beg);
  float inv = 1.0f / fmaxf(deg, 1.0f);
  float self = bf2f(x16[i * DD + j]);
  out[i * DD + j] = fmaxf(fmaf(acc, inv, self + bias[j]), 0.0f);
}

extern "C" void kernel_launch(void* const* d_in, const int* in_sizes, int n_in,
                              void* d_out, int out_size, void* d_ws, size_t ws_size,
                              hipStream_t stream) {
  const float* nf    = (const float*)d_in[0];
  const int*   ei    = (const int*)d_in[1];
  const float* W     = (const float*)d_in[2];
  const float* b_lin = (const float*)d_in[3];
  const float* bias  = (const float*)d_in[4];
  float* out = (float*)d_out;

  // workspace layout (x16 at base: gather's clamped reads stay in-bounds)
  u16* x16     = (u16*)d_ws;                       // N*D bf16   (6.4 MB)
  u16* csr_src = x16 + (size_t)NN * DD;            // E u16 + 64 pad (1.6 MB)
  int* csr_off = (int*)(csr_src + EE + 64);        // N+1 ints
  int* cur     = csr_off + (NN + 1);               // N ints
  int* cnt     = cur + NN;                         // N ints
  // total ~8.6 MB << ws_size

  hipMemsetAsync(cnt, 0, (size_t)NN * sizeof(int), stream);
  linear_hist_kernel<<<NBLKL + NHIST, 256, 0, stream>>>(nf, W, b_lin, ei, x16, cnt);
  scan_kernel<<<NB, 256, 0, stream>>>(cnt, csr_off, cur);
  scatter_kernel<<<NSLICE * 8, 256, 0, stream>>>(ei, cur, csr_src);
  gather_kernel<<<NN / 4, 256, 0, stream>>>(x16, csr_src, csr_off, bias, out);
}

// Round 10
// 186.096 us; speedup vs baseline: 2.4477x; 1.0931x over previous
//
#include <hip/hip_runtime.h>
#include <hip/hip_bf16.h>

#define NN 50000
#define EE 800000
#define NB 196      // ceil(NN/256) scan blocks
#define NTILE 3125  // NN/16 row tiles (exact)
#define NBLKL 391   // ceil(NTILE/8) linear blocks (8 tiles/block, 2/wave)
#define NSLICE 128  // edge slices for scatter
#define ESL 6250    // EE/NSLICE edges per slice
#define DRNG 6250   // NN/8 dst nodes per XCD range
#define DD 64

typedef unsigned short u16;
typedef unsigned int u32;
typedef __attribute__((ext_vector_type(8))) short bf16x8;
typedef __attribute__((ext_vector_type(4))) float f32x4;

__device__ __forceinline__ float bf2f(u16 u) {
  u32 t = ((u32)u) << 16;
  return __builtin_bit_cast(float, t);
}
__device__ __forceinline__ u16 f2bf(float f) {
  u32 b = __builtin_bit_cast(u32, f);
  u32 r = (b + 0x7FFF + ((b >> 16) & 1)) >> 16;
  return (u16)r;
}

// ---------------------------------------------------------------------------
// Kernel 1 (MFMA, R6-proven): x = nf @ W.T + b_lin, bf16 out. Zeroes cnt[].
// 2 row-tiles per wave (8/block). C/D: col=lane&15, row=(lane>>4)*4+reg.
// ---------------------------------------------------------------------------
__global__ __launch_bounds__(256) void linear_mfma_kernel(
    const float* __restrict__ nf, const float* __restrict__ W,
    const float* __restrict__ b_lin, u16* __restrict__ x16,
    int* __restrict__ cnt) {
  __shared__ u16 Wsh[64 * 72];
  int tid = threadIdx.x;

  if (blockIdx.x < NB) {  // fold hist-counter zeroing into this dispatch
    int zi = blockIdx.x * 256 + tid;
    if (zi < NN) cnt[zi] = 0;
  }

#pragma unroll
  for (int s = 0; s < 16; ++s) {
    int idx = s * 256 + tid;
    int j = idx >> 6, k = idx & 63;
    Wsh[j * 72 + k] = f2bf(W[idx]);
  }
  __syncthreads();

  int wave = tid >> 6;
  int lane = tid & 63;
  int m = lane & 15;
  int quad = lane >> 4;

  bf16x8 bfrag[4][2];
#pragma unroll
  for (int c = 0; c < 4; ++c) {
#pragma unroll
    for (int ks = 0; ks < 2; ++ks) {
      const u16* p = &Wsh[(c * 16 + m) * 72 + ks * 32 + quad * 8];
      bfrag[c][ks] = *(const bf16x8*)p;
    }
  }

#pragma unroll
  for (int tt = 0; tt < 2; ++tt) {
    int tile = blockIdx.x * 8 + wave * 2 + tt;
    if (tile >= NTILE) continue;
    int rowbase = tile * 16;

    bf16x8 afrag[2];
#pragma unroll
    for (int ks = 0; ks < 2; ++ks) {
      const float* p = nf + (rowbase + m) * DD + ks * 32 + quad * 8;
      float4 lo = *(const float4*)p;
      float4 hi = *(const float4*)(p + 4);
      bf16x8 a;
      a[0] = (short)f2bf(lo.x); a[1] = (short)f2bf(lo.y);
      a[2] = (short)f2bf(lo.z); a[3] = (short)f2bf(lo.w);
      a[4] = (short)f2bf(hi.x); a[5] = (short)f2bf(hi.y);
      a[6] = (short)f2bf(hi.z); a[7] = (short)f2bf(hi.w);
      afrag[ks] = a;
    }

    f32x4 acc[4];
#pragma unroll
    for (int c = 0; c < 4; ++c) {
      acc[c][0] = 0.0f; acc[c][1] = 0.0f; acc[c][2] = 0.0f; acc[c][3] = 0.0f;
    }
#pragma unroll
    for (int c = 0; c < 4; ++c) {
      acc[c] = __builtin_amdgcn_mfma_f32_16x16x32_bf16(afrag[0], bfrag[c][0], acc[c], 0, 0, 0);
      acc[c] = __builtin_amdgcn_mfma_f32_16x16x32_bf16(afrag[1], bfrag[c][1], acc[c], 0, 0, 0);
    }

#pragma unroll
    for (int c = 0; c < 4; ++c) {
      int gcol = c * 16 + m;
      float bl = b_lin[gcol];
#pragma unroll
      for (int r = 0; r < 4; ++r) {
        int grow = rowbase + quad * 4 + r;
        x16[grow * DD + gcol] = f2bf(acc[c][r] + bl);
      }
    }
  }
}

// ---------------------------------------------------------------------------
// hist (R6): 4 edges per thread, atomic per-dst counts.
// ---------------------------------------------------------------------------
__global__ __launch_bounds__(256) void hist_kernel(
    const int* __restrict__ ei, int* __restrict__ cnt) {
  int e = (blockIdx.x * 256 + threadIdx.x) * 4;
  if (e >= EE) return;
  int4 a = *(const int4*)(ei + 2 * e);
  int4 b = *(const int4*)(ei + 2 * e + 4);
  atomicAdd(&cnt[a.y], 1);
  atomicAdd(&cnt[a.w], 1);
  atomicAdd(&cnt[b.y], 1);
  atomicAdd(&cnt[b.w], 1);
}

// ---------------------------------------------------------------------------
// scan1 (R6): per-block sums of cnt -> partial[196]
// ---------------------------------------------------------------------------
__global__ __launch_bounds__(256) void scan1_kernel(
    const int* __restrict__ cnt, int* __restrict__ partial) {
  __shared__ int s[256];
  int t = threadIdx.x;
  int i = blockIdx.x * 256 + t;
  s[t] = (i < NN) ? cnt[i] : 0;
  __syncthreads();
#pragma unroll
  for (int o = 128; o > 0; o >>= 1) {
    if (t < o) s[t] += s[t + o];
    __syncthreads();
  }
  if (t == 0) partial[blockIdx.x] = s[0];
}

// ---------------------------------------------------------------------------
// scan23 (R6): redundant scan of partial[] + local chunk scan.
// ---------------------------------------------------------------------------
__global__ __launch_bounds__(256) void scan23_kernel(
    const int* __restrict__ cnt, const int* __restrict__ partial,
    int* __restrict__ csr_off, int* __restrict__ cur) {
  __shared__ int sp[256];
  __shared__ int s[256];
  __shared__ int boff;
  int t = threadIdx.x;

  int pv = (t < NB) ? partial[t] : 0;
  sp[t] = pv;
  __syncthreads();
#pragma unroll
  for (int o = 1; o < 256; o <<= 1) {
    int u = (t >= o) ? sp[t - o] : 0;
    __syncthreads();
    sp[t] += u;
    __syncthreads();
  }
  if (t == 0) boff = (blockIdx.x > 0) ? sp[blockIdx.x - 1] : 0;
  __syncthreads();

  int i = blockIdx.x * 256 + t;
  int v = (i < NN) ? cnt[i] : 0;
  s[t] = v;
  __syncthreads();
#pragma unroll
  for (int o = 1; o < 256; o <<= 1) {
    int u = (t >= o) ? s[t - o] : 0;
    __syncthreads();
    s[t] += u;
    __syncthreads();
  }
  int off = boff + s[t] - v;
  if (i < NN) {
    csr_off[i] = off;
    cur[i] = off;
    if (i == NN - 1) csr_off[NN] = off + v;
  }
}

// ---------------------------------------------------------------------------
// scatter (R6): XCD-sliced. Block b: dst range r=b&7, edge slice sl=b>>3.
// ---------------------------------------------------------------------------
__global__ __launch_bounds__(256) void scatter_kernel(
    const int* __restrict__ ei, int* __restrict__ cur,
    u16* __restrict__ csr_src) {
  int r = blockIdx.x & 7;
  int sl = blockIdx.x >> 3;
  int rlo = r * DRNG;
  int ebase = sl * ESL;
  int eend = ebase + ESL;
#pragma unroll 1
  for (int it = 0; it < 13; ++it) {
    int e = ebase + it * 512 + (int)threadIdx.x * 2;
    if (e < eend) {
      int4 p = *(const int4*)(ei + 2 * e);
      if ((u32)(p.y - rlo) < (u32)DRNG) {
        int pos = atomicAdd(&cur[p.y], 1);
        csr_src[pos] = (u16)p.x;
      }
      if ((u32)(p.w - rlo) < (u32)DRNG) {
        int pos = atomicAdd(&cur[p.w], 1);
        csr_src[pos] = (u16)p.z;
      }
    }
  }
}

// ---------------------------------------------------------------------------
// gather v2: lane j covers features (j&15)*4..+4 of edge k+(j>>4).
// One uint2 load = 4 edges' rows per instruction (4x fewer VMEM insts than
// the per-edge ushort scheme). Phases kept separate (bpermute-all ->
// load-all -> accumulate-all) so loads stay independent (MLP = 16 lines).
// Lanes beyond win clamp to last valid edge (dup line, L1-hot), adds gated.
// Cross-quad butterfly reduce, float4 epilogue store by 16 lanes.
// ---------------------------------------------------------------------------
__global__ __launch_bounds__(256) void gather_kernel(
    const u16* __restrict__ x16, const u16* __restrict__ csr_src,
    const int* __restrict__ csr_off, const float* __restrict__ bias,
    float* __restrict__ out) {
  int i = blockIdx.x * 4 + (threadIdx.x >> 6);  // grid exact: NN/4 blocks
  int j = threadIdx.x & 63;
  int fg = j & 15;  // feature group: 4 floats
  int q = j >> 4;   // quad -> edge offset within batch of 4
  int beg = __builtin_amdgcn_readfirstlane(csr_off[i]);
  int end = __builtin_amdgcn_readfirstlane(csr_off[i + 1]);
  float4 acc = make_float4(0.0f, 0.0f, 0.0f, 0.0f);
  int pos = beg;
#pragma unroll 1
  while (pos < end) {  // 1 iteration for deg<=64 (always, in practice)
    int my = (int)csr_src[pos + j];  // coalesced 128 B (csr_src padded)
    int win = end - pos;
    win = win > 64 ? 64 : win;
    int srcv[16];
    uint2 dv[16];
    // phase 1: per-quad srcs via bpermute (independent)
#pragma unroll
    for (int kb = 0; kb < 4; ++kb) {
      if (kb * 16 < win) {  // scalar branch
#pragma unroll
        for (int u = 0; u < 4; ++u) {
          int e = kb * 16 + u * 4 + q;
          int ec = e < win ? e : win - 1;  // clamp
          srcv[kb * 4 + u] = __shfl(my, ec, 64);
        }
      }
    }
    // phase 2: all loads issue back-to-back
#pragma unroll
    for (int kb = 0; kb < 4; ++kb) {
      if (kb * 16 < win) {
#pragma unroll
        for (int u = 0; u < 4; ++u) {
          int idx = kb * 4 + u;
          dv[idx] = *(const uint2*)(x16 + (size_t)srcv[idx] * DD + fg * 4);
        }
      }
    }
    // phase 3: unpack + gated accumulate
#pragma unroll
    for (int kb = 0; kb < 4; ++kb) {
      if (kb * 16 < win) {
#pragma unroll
        for (int u = 0; u < 4; ++u) {
          int idx = kb * 4 + u;
          int e = kb * 16 + u * 4 + q;
          bool val = e < win;
          uint2 d = dv[idx];
          float f0 = bf2f((u16)(d.x & 0xFFFFu));
          float f1 = bf2f((u16)(d.x >> 16));
          float f2 = bf2f((u16)(d.y & 0xFFFFu));
          float f3 = bf2f((u16)(d.y >> 16));
          acc.x += val ? f0 : 0.0f;
          acc.y += val ? f1 : 0.0f;
          acc.z += val ? f2 : 0.0f;
          acc.w += val ? f3 : 0.0f;
        }
      }
    }
    pos += 64;
  }
  // cross-quad reduce: lanes j, j^16, j^32, j^48 share a feature group
#pragma unroll
  for (int mk = 16; mk <= 32; mk <<= 1) {
    acc.x += __shfl_xor(acc.x, mk, 64);
    acc.y += __shfl_xor(acc.y, mk, 64);
    acc.z += __shfl_xor(acc.z, mk, 64);
    acc.w += __shfl_xor(acc.w, mk, 64);
  }
  if (q == 0) {  // 16 lanes store the full 64-float row as float4
    float deg = (float)(end - beg);
    float inv = 1.0f / fmaxf(deg, 1.0f);
    uint2 sv = *(const uint2*)(x16 + (size_t)i * DD + fg * 4);
    float4 bv = *(const float4*)(bias + fg * 4);
    float4 o;
    o.x = fmaxf(fmaf(acc.x, inv, bf2f((u16)(sv.x & 0xFFFFu)) + bv.x), 0.0f);
    o.y = fmaxf(fmaf(acc.y, inv, bf2f((u16)(sv.x >> 16)) + bv.y), 0.0f);
    o.z = fmaxf(fmaf(acc.z, inv, bf2f((u16)(sv.y & 0xFFFFu)) + bv.z), 0.0f);
    o.w = fmaxf(fmaf(acc.w, inv, bf2f((u16)(sv.y >> 16)) + bv.w), 0.0f);
    *(float4*)(out + (size_t)i * DD + fg * 4) = o;
  }
}

extern "C" void kernel_launch(void* const* d_in, const int* in_sizes, int n_in,
                              void* d_out, int out_size, void* d_ws, size_t ws_size,
                              hipStream_t stream) {
  const float* nf    = (const float*)d_in[0];
  const int*   ei    = (const int*)d_in[1];
  const float* W     = (const float*)d_in[2];
  const float* b_lin = (const float*)d_in[3];
  const float* bias  = (const float*)d_in[4];
  float* out = (float*)d_out;

  // workspace layout (x16 at base: gather's clamped reads stay in-bounds)
  u16* x16     = (u16*)d_ws;                       // N*D bf16   (6.4 MB)
  u16* csr_src = x16 + (size_t)NN * DD;            // E u16 + 64 pad (1.6 MB)
  int* csr_off = (int*)(csr_src + EE + 64);        // N+1 ints
  int* cur     = csr_off + (NN + 1);               // N ints
  int* cnt     = cur + NN;                         // N ints
  int* partial = cnt + NN;                         // NB ints
  // total ~8.6 MB << ws_size

  linear_mfma_kernel<<<NBLKL, 256, 0, stream>>>(nf, W, b_lin, x16, cnt);
  hist_kernel<<<(EE / 4 + 255) / 256, 256, 0, stream>>>(ei, cnt);
  scan1_kernel<<<NB, 256, 0, stream>>>(cnt, partial);
  scan23_kernel<<<NB, 256, 0, stream>>>(cnt, partial, csr_off, cur);
  scatter_kernel<<<NSLICE * 8, 256, 0, stream>>>(ei, cur, csr_src);
  gather_kernel<<<NN / 4, 256, 0, stream>>>(x16, csr_src, csr_off, bias, out);
}